// Round 13
// baseline (303.089 us; speedup 1.0000x reference)
//
#include <hip/hip_runtime.h>
#include <hip/hip_bf16.h>

#define NN 50000
#define EE 800000
#define DD 128
#define CC 40
#define NEG 0.2f
#define NPAD 50048   // NN rounded up to 128 multiple
#define NB 782       // buckets of 64 nodes
#define CEDGES 2048  // edges per block in bucket sort (391 blocks)
#define PADCAP 2048  // padded slots per bucket
#define NCB 391      // bucketC blocks
#define WOFF 391     // W-pack blocks start
#define POFF 583     // param-cvt blocks start
#define HOFF 608     // housekeeping block

typedef _Float16 half8 __attribute__((ext_vector_type(8)));
typedef unsigned short ushort8 __attribute__((ext_vector_type(8)));
typedef float floatx4 __attribute__((ext_vector_type(4)));

__device__ __forceinline__ float lrelu(float a) { return a > 0.f ? a : NEG * a; }
__device__ __forceinline__ float bf2f(unsigned short u) {
    union { unsigned int i; float f; } v; v.i = (unsigned int)u << 16; return v.f;
}

__device__ __forceinline__ int edge_at(const void* ei, int i64, long long idx) {
    return i64 ? (int)((const long long*)ei)[idx] : ((const int*)ei)[idx];
}

// ---------- merged: bucketC (blocks 0..390) + detect/param-cvt/W-pack ----------
struct ParamCvt {
    const void* src[11];
    int off[11];
    int total;
};

__global__ __launch_bounds__(256) void cvt_bucketC(ParamCvt a,
                                                   const void* __restrict__ x_raw,
                                                   const void* __restrict__ ei,
                                                   const void* __restrict__ W0,
                                                   const void* __restrict__ W1,
                                                   const void* __restrict__ W2,
                                                   int* __restrict__ flags,
                                                   int* __restrict__ cursor,
                                                   float* __restrict__ params,
                                                   _Float16* __restrict__ wpack,
                                                   unsigned int* __restrict__ pairs) {
    int lane = threadIdx.x & 63;
    if (blockIdx.x < NCB) {
        // ---- bucketC: padded-bucket counting sort (self-detects i64) ----
        __shared__ int cnt[NB];
        __shared__ int loff[NB];
        __shared__ int gbase[NB];
        __shared__ unsigned int lp[CEDGES];
        __shared__ int wsum[4];
        __shared__ int carry;
        int t = threadIdx.x, wid = t >> 6;
        unsigned int hi = ((const unsigned int*)ei)[2 * lane + 1];
        int i64 = (__ballot(hi != 0u) == 0ull) ? 1 : 0;
        for (int i = t; i < NB; i += 256) cnt[i] = 0;
        if (t == 0) carry = 0;
        __syncthreads();
        int base = blockIdx.x * CEDGES;
        int sreg[8], dreg[8];
        #pragma unroll
        for (int j = 0; j < 8; ++j) {
            int e = base + j * 256 + t;
            if (e < EE) {
                sreg[j] = edge_at(ei, i64, e);
                dreg[j] = edge_at(ei, i64, (long long)EE + e);
                atomicAdd(&cnt[dreg[j] >> 6], 1);
            } else { sreg[j] = -1; dreg[j] = -1; }
        }
        __syncthreads();
        for (int c0 = 0; c0 < NB; c0 += 256) {
            int i = c0 + t;
            int v = (i < NB) ? cnt[i] : 0;
            int x = v;
            #pragma unroll
            for (int o = 1; o < 64; o <<= 1) {
                int y = __shfl_up(x, o, 64);
                if (lane >= o) x += y;
            }
            if (lane == 63) wsum[wid] = x;
            __syncthreads();
            int carr = carry;
            int woff = 0;
            for (int w = 0; w < wid; ++w) woff += wsum[w];
            if (i < NB) loff[i] = carr + woff + x - v;
            __syncthreads();
            if (t == 0) carry = carr + wsum[0] + wsum[1] + wsum[2] + wsum[3];
            __syncthreads();
        }
        for (int i = t; i < NB; i += 256) {
            int c = cnt[i];
            gbase[i] = c ? atomicAdd(&cursor[i], c) : 0;
        }
        __syncthreads();
        for (int i = t; i < NB; i += 256) cnt[i] = loff[i];
        __syncthreads();
        #pragma unroll
        for (int j = 0; j < 8; ++j) {
            if (dreg[j] >= 0) {
                int slot = atomicAdd(&cnt[dreg[j] >> 6], 1);
                lp[slot] = ((unsigned int)dreg[j] << 16) | (unsigned int)sreg[j];
            }
        }
        __syncthreads();
        int total = (EE - base < CEDGES) ? (EE - base) : CEDGES;
        for (int i = t; i < total; i += 256) {
            unsigned int pr = lp[i];
            int b = (int)(pr >> 22);
            int idx = gbase[b] + (i - loff[b]);
            if (idx < PADCAP)
                __builtin_nontemporal_store(pr, &pairs[(size_t)b * PADCAP + idx]);
        }
        return;
    }
    // ---- dtype probe (per wave) ----
    unsigned short u = ((const unsigned short*)x_raw)[lane * 2];
    int e = (u >> 7) & 0xFF;
    int bad = (!(e >= 96 && e <= 158) && u != 0 && u != 0x8000) ? 1 : 0;
    int bf = (__ballot(bad) == 0ull) ? 1 : 0;
    if (blockIdx.x == HOFF) {   // flags for downstream kernels
        unsigned int hi = ((const unsigned int*)ei)[2 * lane + 1];
        int i64 = (__ballot(hi != 0u) == 0ull) ? 1 : 0;
        if (threadIdx.x == 0) { flags[0] = bf; flags[1] = i64; }
        return;
    }
    if (blockIdx.x < POFF) {   // pack W: 3*16384 elements, blocks WOFF..582
        int i = (blockIdx.x - WOFF) * 256 + threadIdx.x;
        int l = i >> 14, r = i & 16383;
        int j = r & 7, ln = (r >> 3) & 63, ks = (r >> 9) & 3, c = r >> 11;
        int k = ks * 32 + (ln >> 4) * 8 + j;
        int ncol = c * 16 + (ln & 15);
        const void* W = (l == 0) ? W0 : ((l == 1) ? W1 : W2);
        float v = bf ? bf2f(((const unsigned short*)W)[k * 128 + ncol])
                     : ((const float*)W)[k * 128 + ncol];
        wpack[i] = (_Float16)v;
    } else {
        int i = (blockIdx.x - POFF) * 256 + threadIdx.x;
        if (i >= a.total) return;
        int k = 0;
        #pragma unroll
        for (int j = 1; j < 11; ++j) if (i >= a.off[j]) k = j;
        int local = i - a.off[k];
        params[i] = bf ? bf2f(((const unsigned short*)a.src[k])[local])
                       : ((const float*)a.src[k])[local];
    }
}

// ---------- MFMA GEMM core (LDS-staged W, 64 rows/block) + fused logits ----------
__device__ __forceinline__ void gemm_core(const half8 a[4], const _Float16* __restrict__ lw,
                                          const float* __restrict__ asrc,
                                          const float* __restrict__ adst,
                                          _Float16* __restrict__ H,
                                          float* __restrict__ es, float* __restrict__ ed,
                                          int n, int rowbase, int lane) {
    int quad = lane >> 4, col = lane & 15;
    float esp[4] = {0, 0, 0, 0}, edp[4] = {0, 0, 0, 0};
    #pragma unroll
    for (int c = 0; c < 8; ++c) {
        floatx4 acc = {0.f, 0.f, 0.f, 0.f};
        #pragma unroll
        for (int ks = 0; ks < 4; ++ks) {
            half8 b = *(const half8*)&lw[(((c * 4 + ks) * 64) + lane) * 8];
            acc = __builtin_amdgcn_mfma_f32_16x16x32_f16(a[ks], b, acc, 0, 0, 0);
        }
        float av = asrc[c * 16 + col], dv = adst[c * 16 + col];
        #pragma unroll
        for (int r = 0; r < 4; ++r) {
            int rowg = rowbase + quad * 4 + r;
            if (rowg < n) H[(size_t)rowg * 128 + c * 16 + col] = (_Float16)acc[r];
            esp[r] += acc[r] * av;
            edp[r] += acc[r] * dv;
        }
    }
    #pragma unroll
    for (int r = 0; r < 4; ++r) {
        float s = esp[r], d = edp[r];
        #pragma unroll
        for (int o = 1; o < 16; o <<= 1) {
            s += __shfl_xor(s, o, 64);
            d += __shfl_xor(d, o, 64);
        }
        int rowg = rowbase + quad * 4 + r;
        if (col == 0 && rowg < n) { es[rowg] = s; ed[rowg] = d; }
    }
}

__global__ __launch_bounds__(256) void gemm_esd_mfma(const _Float16* __restrict__ X,
                                                     const _Float16* __restrict__ Wp,
                                                     const float* __restrict__ asrc,
                                                     const float* __restrict__ adst,
                                                     _Float16* __restrict__ H,
                                                     float* __restrict__ es,
                                                     float* __restrict__ ed, int n) {
    __shared__ _Float16 lw[16384];
    for (int i = threadIdx.x; i < 2048; i += 256)
        ((half8*)lw)[i] = ((const half8*)Wp)[i];
    int w = threadIdx.x >> 6, lane = threadIdx.x & 63;
    int quad = lane >> 4, col = lane & 15;
    int rowbase = blockIdx.x * 64 + w * 16;
    half8 a[4];
    const _Float16* xrow = X + (size_t)(rowbase + col) * 128 + quad * 8;
    #pragma unroll
    for (int ks = 0; ks < 4; ++ks) a[ks] = *(const half8*)(xrow + ks * 32);
    __syncthreads();
    gemm_core(a, lw, asrc, adst, H, es, ed, n, rowbase, lane);
}

// ---------- merged: bucketD (blocks 0..NB-1) + layer-0 gemm (blocks NB..) ----------
__global__ __launch_bounds__(256) void bucketD_gemm0(const unsigned int* __restrict__ pairs,
                                                     const int* __restrict__ cursor,
                                                     int* __restrict__ begA,
                                                     int* __restrict__ endA,
                                                     unsigned short* __restrict__ csr,
                                                     const void* __restrict__ Xraw,
                                                     const int* __restrict__ flags,
                                                     const _Float16* __restrict__ Wp,
                                                     const float* __restrict__ asrc,
                                                     const float* __restrict__ adst,
                                                     _Float16* __restrict__ H,
                                                     float* __restrict__ es,
                                                     float* __restrict__ ed, int n) {
    __shared__ _Float16 lw[16384];
    __shared__ int cntS[64];
    __shared__ int curS[64];
    int t = threadIdx.x;
    if (blockIdx.x < NB) {
        // ---- bucketD ----
        int b = blockIdx.x;
        int cntb = cursor[b];
        if (cntb > PADCAP) cntb = PADCAP;
        int pbeg = b * PADCAP;
        if (t < 64) cntS[t] = 0;
        __syncthreads();
        for (int i = t; i < cntb; i += 256)
            atomicAdd(&cntS[(pairs[pbeg + i] >> 16) & 63], 1);
        __syncthreads();
        if (t < 64) {
            int v = cntS[t];
            int x = v;
            #pragma unroll
            for (int o = 1; o < 64; o <<= 1) {
                int y = __shfl_up(x, o, 64);
                if (t >= o) x += y;
            }
            int excl = x - v;
            curS[t] = excl;
            int gid = b * 64 + t;
            if (gid < NN) { begA[gid] = pbeg + excl; endA[gid] = pbeg + excl + v; }
        }
        __syncthreads();
        for (int i = t; i < cntb; i += 256) {
            unsigned int pr = pairs[pbeg + i];
            int node = (pr >> 16) & 63;
            int p = atomicAdd(&curS[node], 1);
            csr[pbeg + p] = (unsigned short)(pr & 0xFFFF);
        }
        return;
    }
    // ---- layer-0 gemm (64 rows/block) ----
    int gb = blockIdx.x - NB;
    for (int i = t; i < 2048; i += 256)
        ((half8*)lw)[i] = ((const half8*)Wp)[i];
    int w = t >> 6, lane = t & 63;
    int quad = lane >> 4, col = lane & 15;
    int rowbase = gb * 64 + w * 16;
    half8 a[4];
    int bf = flags[0];
    int row = rowbase + col;
    if (row >= n) row = n - 1;   // clamp; results discarded
    if (bf) {
        const unsigned short* xr = (const unsigned short*)Xraw + (size_t)row * 128 + quad * 8;
        #pragma unroll
        for (int ks = 0; ks < 4; ++ks) {
            ushort8 u = *(const ushort8*)(xr + ks * 32);
            #pragma unroll
            for (int j = 0; j < 8; ++j) a[ks][j] = (_Float16)bf2f(u[j]);
        }
    } else {
        const float* xr = (const float*)Xraw + (size_t)row * 128 + quad * 8;
        #pragma unroll
        for (int ks = 0; ks < 4; ++ks) {
            float4 f0 = *(const float4*)(xr + ks * 32);
            float4 f1 = *(const float4*)(xr + ks * 32 + 4);
            a[ks][0] = (_Float16)f0.x; a[ks][1] = (_Float16)f0.y;
            a[ks][2] = (_Float16)f0.z; a[ks][3] = (_Float16)f0.w;
            a[ks][4] = (_Float16)f1.x; a[ks][5] = (_Float16)f1.y;
            a[ks][6] = (_Float16)f1.z; a[ks][7] = (_Float16)f1.w;
        }
    }
    __syncthreads();
    gemm_core(a, lw, asrc, adst, H, es, ed, n, rowbase, lane);
}

// ---------- segment softmax + aggregation + bias + ReLU ----------
// 2 nodes per wave (32 lanes each = 2 groups x 16 lanes); LDS exp-cache;
// stride-2 edge split gives each lane 8 independent gathers per iteration.
__global__ __launch_bounds__(256) void agg_kernel(const _Float16* __restrict__ H,
                                                  const int* __restrict__ begA,
                                                  const int* __restrict__ endA,
                                                  const unsigned short* __restrict__ csr,
                                                  const float* __restrict__ es,
                                                  const float* __restrict__ ed,
                                                  const float* __restrict__ bias,
                                                  _Float16* __restrict__ Xout, int n) {
    __shared__ float ex_all[8][64];
    int lane = threadIdx.x & 63;
    int w = threadIdx.x >> 6;
    int half = lane >> 5;                // node within wave
    int hl = lane & 31;                  // lane within half-wave
    int nodeSlot = w * 2 + half;
    int node = blockIdx.x * 8 + nodeSlot;
    if (node >= n) return;
    float* exsh = ex_all[nodeSlot];
    int beg = begA[node], end = endA[node];
    int total = end - beg;
    float edi = ed[node];
    float wself = __expf(lrelu(es[node] + edi));

    // pass 1: exp(alpha) -> LDS (unnormalized), z-reduce over 32 lanes
    float ex0 = 0.f, ex1 = 0.f;
    if (hl < total) ex0 = __expf(lrelu(es[csr[beg + hl]] + edi));
    if (hl + 32 < total) ex1 = __expf(lrelu(es[csr[beg + hl + 32]] + edi));
    if (hl < total) exsh[hl] = ex0;
    if (hl + 32 < total) exsh[hl + 32] = ex1;
    float zloc = ex0 + ex1;
    for (int e = beg + hl + 64; e < end; e += 32)
        zloc += __expf(lrelu(es[csr[e]] + edi));
    #pragma unroll
    for (int o = 16; o > 0; o >>= 1) zloc += __shfl_xor(zloc, o, 64);
    float invz = 1.f / (zloc + wself);

    // pass 2: 2 groups x 16 lanes; group g takes edges == g (mod 2); 8-deep
    int g = (lane >> 4) & 1;
    int sub = lane & 15;
    int f0 = sub * 8;
    float acc[8] = {0, 0, 0, 0, 0, 0, 0, 0};
    if (g == 0) {
        half8 h = *(const half8*)&H[(size_t)node * 128 + f0];
        #pragma unroll
        for (int j = 0; j < 8; ++j) acc[j] = wself * (float)h[j];
    }
    for (int base = 0; base < total; base += 16) {
        int sdx[8]; float wdx[8];
        #pragma unroll
        for (int d = 0; d < 8; ++d) {
            int sl = base + g + 2 * d;
            if (sl < total) {
                int si = csr[beg + sl];
                sdx[d] = si;
                wdx[d] = (sl < 64) ? exsh[sl] : __expf(lrelu(es[si] + edi));
            } else { sdx[d] = node; wdx[d] = 0.f; }
        }
        half8 h[8];
        #pragma unroll
        for (int d = 0; d < 8; ++d)
            h[d] = *(const half8*)&H[(size_t)sdx[d] * 128 + f0];
        #pragma unroll
        for (int d = 0; d < 8; ++d) {
            #pragma unroll
            for (int j = 0; j < 8; ++j) acc[j] += wdx[d] * (float)h[d][j];
        }
    }
    // combine the 2 groups (xor lane bit 4)
    #pragma unroll
    for (int j = 0; j < 8; ++j) acc[j] += __shfl_xor(acc[j], 16, 64);
    if ((lane & 16) == 0) {
        half8 o8;
        #pragma unroll
        for (int j = 0; j < 8; ++j)
            o8[j] = (_Float16)fmaxf(acc[j] * invz + bias[f0 + j], 0.f);
        __builtin_nontemporal_store(o8, (half8*)&Xout[(size_t)node * 128 + f0]);
    }
}

// ---------- head ----------
__global__ __launch_bounds__(256) void head_kernel(const _Float16* __restrict__ X,
                                                   const float* __restrict__ Whf,
                                                   const float* __restrict__ bhf,
                                                   const int* __restrict__ flags,
                                                   void* __restrict__ out, int n) {
    __shared__ float ws[128 * 40];
    __shared__ float xs[64 * 129];
    int bm = blockIdx.x * 64;
    for (int t = threadIdx.x; t < 128 * 40; t += 256) ws[t] = Whf[t];
    for (int t = threadIdx.x; t < 64 * 16; t += 256) {
        int r = t >> 4, c8 = t & 15;
        half8 v = __builtin_nontemporal_load((const half8*)&X[(size_t)(bm + r) * 128 + c8 * 8]);
        #pragma unroll
        for (int j = 0; j < 8; ++j) xs[r * 129 + c8 * 8 + j] = (float)v[j];
    }
    __syncthreads();
    int r = threadIdx.x >> 2, cg = threadIdx.x & 3;
    int c0 = cg * 10;
    float acc[10] = {};
    for (int k = 0; k < 128; ++k) {
        float xr = xs[r * 129 + k];
        #pragma unroll
        for (int j = 0; j < 10; ++j) acc[j] += xr * ws[k * 40 + c0 + j];
    }
    int row = bm + r;
    if (row < n) {
        if (flags[0]) {
            __hip_bfloat16* ob = (__hip_bfloat16*)out;
            #pragma unroll
            for (int j = 0; j < 10; ++j)
                ob[row * 40 + c0 + j] = __float2bfloat16(acc[j] + bhf[c0 + j]);
        } else {
            float* of = (float*)out;
            #pragma unroll
            for (int j = 0; j < 10; ++j)
                of[row * 40 + c0 + j] = acc[j] + bhf[c0 + j];
        }
    }
}

extern "C" void kernel_launch(void* const* d_in, const int* in_sizes, int n_in,
                              void* d_out, int out_size, void* d_ws, size_t ws_size,
                              hipStream_t stream) {
    const void* x_raw = d_in[0];
    const void* ei    = d_in[1];

    char* p = (char*)d_ws;
    auto alloc = [&](size_t bytes) { void* r = (void*)p; p += (bytes + 255) & ~(size_t)255; return r; };
    int*            flags  = (int*)alloc(16);
    _Float16*       X      = (_Float16*)alloc((size_t)NPAD * DD * 2);
    _Float16*       H      = (_Float16*)alloc((size_t)NPAD * DD * 2);
    float*          es     = (float*)alloc((size_t)NN * 4);
    float*          ed     = (float*)alloc((size_t)NN * 4);
    int*            begA   = (int*)alloc((size_t)NN * 4);
    int*            endA   = (int*)alloc((size_t)NN * 4);
    unsigned short* csr    = (unsigned short*)alloc((size_t)NB * PADCAP * 2);
    unsigned int*   pairs  = (unsigned int*)alloc((size_t)NB * PADCAP * 4);
    int*            cursor = (int*)alloc((size_t)NB * 4);
    _Float16*       wpack  = (_Float16*)alloc((size_t)3 * 16384 * 2);
    float*          params = (float*)alloc((size_t)(3 * 384 + 5160) * 4);

    ParamCvt pc;
    {
        int k = 0, off = 0;
        auto add = [&](const void* s, int nel) { pc.src[k] = s; pc.off[k] = off; off += nel; ++k; };
        for (int l = 0; l < 3; ++l) {
            add(d_in[3 + 4 * l], 128);
            add(d_in[4 + 4 * l], 128);
            add(d_in[5 + 4 * l], 128);
        }
        add(d_in[14], 5120);
        add(d_in[15], 40);
        pc.total = off;   // 6312
    }
    hipMemsetAsync(cursor, 0, (size_t)NB * 4, stream);
    // blocks: [0,391) bucketC | [391,583) W-pack | [583,608) param-cvt | 608 flags
    cvt_bucketC<<<HOFF + 1, 256, 0, stream>>>(pc, x_raw, ei, d_in[2], d_in[6], d_in[10],
                                              flags, cursor, params, wpack, pairs);

    const int ngb = NPAD / 64;   // 782 blocks of 64 rows
    float* base0 = params;
    bucketD_gemm0<<<NB + ngb, 256, 0, stream>>>(pairs, cursor, begA, endA, csr,
                                                x_raw, flags, wpack, base0, base0 + 128,
                                                H, es, ed, NN);
    agg_kernel<<<(NN + 7) / 8, 256, 0, stream>>>(H, begA, endA, csr, es, ed, base0 + 256, X, NN);

    for (int l = 1; l < 3; ++l) {
        float* base = params + l * 384;
        gemm_esd_mfma<<<ngb, 256, 0, stream>>>(X, wpack + l * 16384, base, base + 128,
                                               H, es, ed, NN);
        agg_kernel<<<(NN + 7) / 8, 256, 0, stream>>>(H, begA, endA, csr, es, ed, base + 256, X, NN);
    }
    head_kernel<<<(NN + 63) / 64, 256, 0, stream>>>(X, params + 1152, params + 1152 + 5120, flags, d_out, NN);
}

// Round 14
// 300.290 us; speedup vs baseline: 1.0093x; 1.0093x over previous
//
#include <hip/hip_runtime.h>
#include <hip/hip_bf16.h>

#define NN 50000
#define EE 800000
#define DD 128
#define CC 40
#define NEG 0.2f
#define NPAD 50048   // NN rounded up to 128 multiple
#define NB 782       // buckets of 64 nodes
#define CEDGES 2048  // edges per block in bucket sort (391 blocks)
#define PADCAP 2048  // padded slots per bucket

typedef _Float16 half8 __attribute__((ext_vector_type(8)));
typedef unsigned short ushort8 __attribute__((ext_vector_type(8)));
typedef float floatx4 __attribute__((ext_vector_type(4)));

__device__ __forceinline__ float lrelu(float a) { return a > 0.f ? a : NEG * a; }
__device__ __forceinline__ float bf2f(unsigned short u) {
    union { unsigned int i; float f; } v; v.i = (unsigned int)u << 16; return v.f;
}

__device__ __forceinline__ int edge_at(const void* ei, int i64, long long idx) {
    return i64 ? (int)((const long long*)ei)[idx] : ((const int*)ei)[idx];
}

// ---------- merged detect + param conversion + W pack + cursor zero ----------
struct ParamCvt {
    const void* src[11];
    int off[11];
    int total;
};

__global__ __launch_bounds__(256) void cvt_all_kernel(ParamCvt a,
                                                      const void* __restrict__ x_raw,
                                                      const void* __restrict__ ei,
                                                      const void* __restrict__ W0,
                                                      const void* __restrict__ W1,
                                                      const void* __restrict__ W2,
                                                      int* __restrict__ flags,
                                                      int* __restrict__ cursor,
                                                      float* __restrict__ params,
                                                      _Float16* __restrict__ wpack) {
    int lane = threadIdx.x & 63;
    unsigned short u = ((const unsigned short*)x_raw)[lane * 2];
    int e = (u >> 7) & 0xFF;
    int bad = (!(e >= 96 && e <= 158) && u != 0 && u != 0x8000) ? 1 : 0;
    int bf = (__ballot(bad) == 0ull) ? 1 : 0;
    if (blockIdx.x == 217) {   // housekeeping block
        unsigned int hi = ((const unsigned int*)ei)[2 * lane + 1];
        int i64 = (__ballot(hi != 0u) == 0ull) ? 1 : 0;
        if (threadIdx.x == 0) { flags[0] = bf; flags[1] = i64; }
        for (int i = threadIdx.x; i < NB; i += 256) cursor[i] = 0;
        return;
    }
    if (blockIdx.x < 192) {   // pack W: 3*16384 elements
        int i = blockIdx.x * 256 + threadIdx.x;
        int l = i >> 14, r = i & 16383;
        int j = r & 7, ln = (r >> 3) & 63, ks = (r >> 9) & 3, c = r >> 11;
        int k = ks * 32 + (ln >> 4) * 8 + j;
        int ncol = c * 16 + (ln & 15);
        const void* W = (l == 0) ? W0 : ((l == 1) ? W1 : W2);
        float v = bf ? bf2f(((const unsigned short*)W)[k * 128 + ncol])
                     : ((const float*)W)[k * 128 + ncol];
        wpack[i] = (_Float16)v;
    } else {
        int i = (blockIdx.x - 192) * 256 + threadIdx.x;
        if (i >= a.total) return;
        int k = 0;
        #pragma unroll
        for (int j = 1; j < 11; ++j) if (i >= a.off[j]) k = j;
        int local = i - a.off[k];
        params[i] = bf ? bf2f(((const unsigned short*)a.src[k])[local])
                       : ((const float*)a.src[k])[local];
    }
}

// ---------- CSR build: padded-bucket counting sort ----------
__global__ __launch_bounds__(256) void bucketC(const void* __restrict__ ei,
                                               const int* __restrict__ flags,
                                               int* __restrict__ cursor,
                                               unsigned int* __restrict__ pairs) {
    __shared__ int cnt[NB];
    __shared__ int loff[NB];
    __shared__ int gbase[NB];
    __shared__ unsigned int lp[CEDGES];
    __shared__ int wsum[4];
    __shared__ int carry;
    int t = threadIdx.x, lane = t & 63, wid = t >> 6;
    for (int i = t; i < NB; i += 256) cnt[i] = 0;
    if (t == 0) carry = 0;
    __syncthreads();
    int base = blockIdx.x * CEDGES;
    int i64 = flags[1];
    int sreg[8], dreg[8];
    #pragma unroll
    for (int j = 0; j < 8; ++j) {
        int e = base + j * 256 + t;
        if (e < EE) {
            sreg[j] = edge_at(ei, i64, e);
            dreg[j] = edge_at(ei, i64, (long long)EE + e);
            atomicAdd(&cnt[dreg[j] >> 6], 1);
        } else { sreg[j] = -1; dreg[j] = -1; }
    }
    __syncthreads();
    for (int c0 = 0; c0 < NB; c0 += 256) {
        int i = c0 + t;
        int v = (i < NB) ? cnt[i] : 0;
        int x = v;
        #pragma unroll
        for (int o = 1; o < 64; o <<= 1) {
            int y = __shfl_up(x, o, 64);
            if (lane >= o) x += y;
        }
        if (lane == 63) wsum[wid] = x;
        __syncthreads();
        int carr = carry;
        int woff = 0;
        for (int w = 0; w < wid; ++w) woff += wsum[w];
        if (i < NB) loff[i] = carr + woff + x - v;
        __syncthreads();
        if (t == 0) carry = carr + wsum[0] + wsum[1] + wsum[2] + wsum[3];
        __syncthreads();
    }
    for (int i = t; i < NB; i += 256) {
        int c = cnt[i];
        gbase[i] = c ? atomicAdd(&cursor[i], c) : 0;
    }
    __syncthreads();
    for (int i = t; i < NB; i += 256) cnt[i] = loff[i];
    __syncthreads();
    #pragma unroll
    for (int j = 0; j < 8; ++j) {
        if (dreg[j] >= 0) {
            int slot = atomicAdd(&cnt[dreg[j] >> 6], 1);
            lp[slot] = ((unsigned int)dreg[j] << 16) | (unsigned int)sreg[j];
        }
    }
    __syncthreads();
    int total = (EE - base < CEDGES) ? (EE - base) : CEDGES;
    for (int i = t; i < total; i += 256) {
        unsigned int pr = lp[i];
        int b = (int)(pr >> 22);
        int idx = gbase[b] + (i - loff[b]);
        if (idx < PADCAP)
            __builtin_nontemporal_store(pr, &pairs[(size_t)b * PADCAP + idx]);
    }
}

// ---------- MFMA GEMM core (LDS-staged W, 64 rows/block) + fused logits ----------
__device__ __forceinline__ void gemm_core(const half8 a[4], const _Float16* __restrict__ lw,
                                          const float* __restrict__ asrc,
                                          const float* __restrict__ adst,
                                          _Float16* __restrict__ H,
                                          float* __restrict__ es, float* __restrict__ ed,
                                          int n, int rowbase, int lane) {
    int quad = lane >> 4, col = lane & 15;
    float esp[4] = {0, 0, 0, 0}, edp[4] = {0, 0, 0, 0};
    #pragma unroll
    for (int c = 0; c < 8; ++c) {
        floatx4 acc = {0.f, 0.f, 0.f, 0.f};
        #pragma unroll
        for (int ks = 0; ks < 4; ++ks) {
            half8 b = *(const half8*)&lw[(((c * 4 + ks) * 64) + lane) * 8];
            acc = __builtin_amdgcn_mfma_f32_16x16x32_f16(a[ks], b, acc, 0, 0, 0);
        }
        float av = asrc[c * 16 + col], dv = adst[c * 16 + col];
        #pragma unroll
        for (int r = 0; r < 4; ++r) {
            int rowg = rowbase + quad * 4 + r;
            if (rowg < n) H[(size_t)rowg * 128 + c * 16 + col] = (_Float16)acc[r];
            esp[r] += acc[r] * av;
            edp[r] += acc[r] * dv;
        }
    }
    #pragma unroll
    for (int r = 0; r < 4; ++r) {
        float s = esp[r], d = edp[r];
        #pragma unroll
        for (int o = 1; o < 16; o <<= 1) {
            s += __shfl_xor(s, o, 64);
            d += __shfl_xor(d, o, 64);
        }
        int rowg = rowbase + quad * 4 + r;
        if (col == 0 && rowg < n) { es[rowg] = s; ed[rowg] = d; }
    }
}

__global__ __launch_bounds__(256) void gemm_esd_mfma(const _Float16* __restrict__ X,
                                                     const _Float16* __restrict__ Wp,
                                                     const float* __restrict__ asrc,
                                                     const float* __restrict__ adst,
                                                     _Float16* __restrict__ H,
                                                     float* __restrict__ es,
                                                     float* __restrict__ ed, int n) {
    __shared__ _Float16 lw[16384];
    for (int i = threadIdx.x; i < 2048; i += 256)
        ((half8*)lw)[i] = ((const half8*)Wp)[i];
    int w = threadIdx.x >> 6, lane = threadIdx.x & 63;
    int quad = lane >> 4, col = lane & 15;
    int rowbase = blockIdx.x * 64 + w * 16;
    half8 a[4];
    const _Float16* xrow = X + (size_t)(rowbase + col) * 128 + quad * 8;
    #pragma unroll
    for (int ks = 0; ks < 4; ++ks) a[ks] = *(const half8*)(xrow + ks * 32);
    __syncthreads();
    gemm_core(a, lw, asrc, adst, H, es, ed, n, rowbase, lane);
}

// ---------- merged: bucketD (blocks 0..NB-1) + layer-0 gemm (blocks NB..) ----------
__global__ __launch_bounds__(256) void bucketD_gemm0(const unsigned int* __restrict__ pairs,
                                                     const int* __restrict__ cursor,
                                                     int* __restrict__ begA,
                                                     int* __restrict__ endA,
                                                     unsigned short* __restrict__ csr,
                                                     const void* __restrict__ Xraw,
                                                     const int* __restrict__ flags,
                                                     const _Float16* __restrict__ Wp,
                                                     const float* __restrict__ asrc,
                                                     const float* __restrict__ adst,
                                                     _Float16* __restrict__ H,
                                                     float* __restrict__ es,
                                                     float* __restrict__ ed, int n) {
    __shared__ _Float16 lw[16384];
    __shared__ int cntS[64];
    __shared__ int curS[64];
    int t = threadIdx.x;
    if (blockIdx.x < NB) {
        // ---- bucketD ----
        int b = blockIdx.x;
        int cntb = cursor[b];
        if (cntb > PADCAP) cntb = PADCAP;
        int pbeg = b * PADCAP;
        if (t < 64) cntS[t] = 0;
        __syncthreads();
        for (int i = t; i < cntb; i += 256)
            atomicAdd(&cntS[(pairs[pbeg + i] >> 16) & 63], 1);
        __syncthreads();
        if (t < 64) {
            int v = cntS[t];
            int x = v;
            #pragma unroll
            for (int o = 1; o < 64; o <<= 1) {
                int y = __shfl_up(x, o, 64);
                if (t >= o) x += y;
            }
            int excl = x - v;
            curS[t] = excl;
            int gid = b * 64 + t;
            if (gid < NN) { begA[gid] = pbeg + excl; endA[gid] = pbeg + excl + v; }
        }
        __syncthreads();
        for (int i = t; i < cntb; i += 256) {
            unsigned int pr = pairs[pbeg + i];
            int node = (pr >> 16) & 63;
            int p = atomicAdd(&curS[node], 1);
            csr[pbeg + p] = (unsigned short)(pr & 0xFFFF);
        }
        return;
    }
    // ---- layer-0 gemm (64 rows/block) ----
    int gb = blockIdx.x - NB;
    for (int i = t; i < 2048; i += 256)
        ((half8*)lw)[i] = ((const half8*)Wp)[i];
    int w = t >> 6, lane = t & 63;
    int quad = lane >> 4, col = lane & 15;
    int rowbase = gb * 64 + w * 16;
    half8 a[4];
    int bf = flags[0];
    int row = rowbase + col;
    if (row >= n) row = n - 1;   // clamp; results discarded
    if (bf) {
        const unsigned short* xr = (const unsigned short*)Xraw + (size_t)row * 128 + quad * 8;
        #pragma unroll
        for (int ks = 0; ks < 4; ++ks) {
            ushort8 u = *(const ushort8*)(xr + ks * 32);
            #pragma unroll
            for (int j = 0; j < 8; ++j) a[ks][j] = (_Float16)bf2f(u[j]);
        }
    } else {
        const float* xr = (const float*)Xraw + (size_t)row * 128 + quad * 8;
        #pragma unroll
        for (int ks = 0; ks < 4; ++ks) {
            float4 f0 = *(const float4*)(xr + ks * 32);
            float4 f1 = *(const float4*)(xr + ks * 32 + 4);
            a[ks][0] = (_Float16)f0.x; a[ks][1] = (_Float16)f0.y;
            a[ks][2] = (_Float16)f0.z; a[ks][3] = (_Float16)f0.w;
            a[ks][4] = (_Float16)f1.x; a[ks][5] = (_Float16)f1.y;
            a[ks][6] = (_Float16)f1.z; a[ks][7] = (_Float16)f1.w;
        }
    }
    __syncthreads();
    gemm_core(a, lw, asrc, adst, H, es, ed, n, rowbase, lane);
}

// ---------- segment softmax + aggregation + bias + ReLU ----------
// 2 nodes per wave (32 lanes each = 2 groups x 16 lanes); LDS exp-cache;
// stride-2 edge split gives each lane 8 independent gathers per iteration.
__global__ __launch_bounds__(256) void agg_kernel(const _Float16* __restrict__ H,
                                                  const int* __restrict__ begA,
                                                  const int* __restrict__ endA,
                                                  const unsigned short* __restrict__ csr,
                                                  const float* __restrict__ es,
                                                  const float* __restrict__ ed,
                                                  const float* __restrict__ bias,
                                                  _Float16* __restrict__ Xout, int n) {
    __shared__ float ex_all[8][64];
    int lane = threadIdx.x & 63;
    int w = threadIdx.x >> 6;
    int half = lane >> 5;                // node within wave
    int hl = lane & 31;                  // lane within half-wave
    int nodeSlot = w * 2 + half;
    int node = blockIdx.x * 8 + nodeSlot;
    if (node >= n) return;
    float* exsh = ex_all[nodeSlot];
    int beg = begA[node], end = endA[node];
    int total = end - beg;
    float edi = ed[node];
    float wself = __expf(lrelu(es[node] + edi));

    // pass 1: exp(alpha) -> LDS (unnormalized), z-reduce over 32 lanes
    float ex0 = 0.f, ex1 = 0.f;
    if (hl < total) ex0 = __expf(lrelu(es[csr[beg + hl]] + edi));
    if (hl + 32 < total) ex1 = __expf(lrelu(es[csr[beg + hl + 32]] + edi));
    if (hl < total) exsh[hl] = ex0;
    if (hl + 32 < total) exsh[hl + 32] = ex1;
    float zloc = ex0 + ex1;
    for (int e = beg + hl + 64; e < end; e += 32)
        zloc += __expf(lrelu(es[csr[e]] + edi));
    #pragma unroll
    for (int o = 16; o > 0; o >>= 1) zloc += __shfl_xor(zloc, o, 64);
    float invz = 1.f / (zloc + wself);

    // pass 2: 2 groups x 16 lanes; group g takes edges == g (mod 2); 8-deep
    int g = (lane >> 4) & 1;
    int sub = lane & 15;
    int f0 = sub * 8;
    float acc[8] = {0, 0, 0, 0, 0, 0, 0, 0};
    if (g == 0) {
        half8 h = *(const half8*)&H[(size_t)node * 128 + f0];
        #pragma unroll
        for (int j = 0; j < 8; ++j) acc[j] = wself * (float)h[j];
    }
    for (int base = 0; base < total; base += 16) {
        int sdx[8]; float wdx[8];
        #pragma unroll
        for (int d = 0; d < 8; ++d) {
            int sl = base + g + 2 * d;
            if (sl < total) {
                int si = csr[beg + sl];
                sdx[d] = si;
                wdx[d] = (sl < 64) ? exsh[sl] : __expf(lrelu(es[si] + edi));
            } else { sdx[d] = node; wdx[d] = 0.f; }
        }
        half8 h[8];
        #pragma unroll
        for (int d = 0; d < 8; ++d)
            h[d] = *(const half8*)&H[(size_t)sdx[d] * 128 + f0];
        #pragma unroll
        for (int d = 0; d < 8; ++d) {
            #pragma unroll
            for (int j = 0; j < 8; ++j) acc[j] += wdx[d] * (float)h[d][j];
        }
    }
    // combine the 2 groups (xor lane bit 4)
    #pragma unroll
    for (int j = 0; j < 8; ++j) acc[j] += __shfl_xor(acc[j], 16, 64);
    if ((lane & 16) == 0) {
        half8 o8;
        #pragma unroll
        for (int j = 0; j < 8; ++j)
            o8[j] = (_Float16)fmaxf(acc[j] * invz + bias[f0 + j], 0.f);
        __builtin_nontemporal_store(o8, (half8*)&Xout[(size_t)node * 128 + f0]);
    }
}

// ---------- head ----------
__global__ __launch_bounds__(256) void head_kernel(const _Float16* __restrict__ X,
                                                   const float* __restrict__ Whf,
                                                   const float* __restrict__ bhf,
                                                   const int* __restrict__ flags,
                                                   void* __restrict__ out, int n) {
    __shared__ float ws[128 * 40];
    __shared__ float xs[64 * 129];
    int bm = blockIdx.x * 64;
    for (int t = threadIdx.x; t < 128 * 40; t += 256) ws[t] = Whf[t];
    for (int t = threadIdx.x; t < 64 * 16; t += 256) {
        int r = t >> 4, c8 = t & 15;
        half8 v = __builtin_nontemporal_load((const half8*)&X[(size_t)(bm + r) * 128 + c8 * 8]);
        #pragma unroll
        for (int j = 0; j < 8; ++j) xs[r * 129 + c8 * 8 + j] = (float)v[j];
    }
    __syncthreads();
    int r = threadIdx.x >> 2, cg = threadIdx.x & 3;
    int c0 = cg * 10;
    float acc[10] = {};
    for (int k = 0; k < 128; ++k) {
        float xr = xs[r * 129 + k];
        #pragma unroll
        for (int j = 0; j < 10; ++j) acc[j] += xr * ws[k * 40 + c0 + j];
    }
    int row = bm + r;
    if (row < n) {
        if (flags[0]) {
            __hip_bfloat16* ob = (__hip_bfloat16*)out;
            #pragma unroll
            for (int j = 0; j < 10; ++j)
                ob[row * 40 + c0 + j] = __float2bfloat16(acc[j] + bhf[c0 + j]);
        } else {
            float* of = (float*)out;
            #pragma unroll
            for (int j = 0; j < 10; ++j)
                of[row * 40 + c0 + j] = acc[j] + bhf[c0 + j];
        }
    }
}

extern "C" void kernel_launch(void* const* d_in, const int* in_sizes, int n_in,
                              void* d_out, int out_size, void* d_ws, size_t ws_size,
                              hipStream_t stream) {
    const void* x_raw = d_in[0];
    const void* ei    = d_in[1];

    char* p = (char*)d_ws;
    auto alloc = [&](size_t bytes) { void* r = (void*)p; p += (bytes + 255) & ~(size_t)255; return r; };
    int*            flags  = (int*)alloc(16);
    _Float16*       X      = (_Float16*)alloc((size_t)NPAD * DD * 2);
    _Float16*       H      = (_Float16*)alloc((size_t)NPAD * DD * 2);
    float*          es     = (float*)alloc((size_t)NN * 4);
    float*          ed     = (float*)alloc((size_t)NN * 4);
    int*            begA   = (int*)alloc((size_t)NN * 4);
    int*            endA   = (int*)alloc((size_t)NN * 4);
    unsigned short* csr    = (unsigned short*)alloc((size_t)NB * PADCAP * 2);
    unsigned int*   pairs  = (unsigned int*)alloc((size_t)NB * PADCAP * 4);
    int*            cursor = (int*)alloc((size_t)NB * 4);
    _Float16*       wpack  = (_Float16*)alloc((size_t)3 * 16384 * 2);
    float*          params = (float*)alloc((size_t)(3 * 384 + 5160) * 4);

    ParamCvt pc;
    {
        int k = 0, off = 0;
        auto add = [&](const void* s, int nel) { pc.src[k] = s; pc.off[k] = off; off += nel; ++k; };
        for (int l = 0; l < 3; ++l) {
            add(d_in[3 + 4 * l], 128);
            add(d_in[4 + 4 * l], 128);
            add(d_in[5 + 4 * l], 128);
        }
        add(d_in[14], 5120);
        add(d_in[15], 40);
        pc.total = off;   // 6312
    }
    cvt_all_kernel<<<218, 256, 0, stream>>>(pc, x_raw, ei, d_in[2], d_in[6], d_in[10],
                                            flags, cursor, params, wpack);

    const int ncb = (EE + CEDGES - 1) / CEDGES;   // 391
    bucketC<<<ncb, 256, 0, stream>>>(ei, flags, cursor, pairs);

    const int ngb = NPAD / 64;   // 782 blocks of 64 rows
    float* base0 = params;
    bucketD_gemm0<<<NB + ngb, 256, 0, stream>>>(pairs, cursor, begA, endA, csr,
                                                x_raw, flags, wpack, base0, base0 + 128,
                                                H, es, ed, NN);
    agg_kernel<<<(NN + 7) / 8, 256, 0, stream>>>(H, begA, endA, csr, es, ed, base0 + 256, X, NN);

    for (int l = 1; l < 3; ++l) {
        float* base = params + l * 384;
        gemm_esd_mfma<<<ngb, 256, 0, stream>>>(X, wpack + l * 16384, base, base + 128,
                                               H, es, ed, NN);
        agg_kernel<<<(NN + 7) / 8, 256, 0, stream>>>(H, begA, endA, csr, es, ed, base + 256, X, NN);
    }
    head_kernel<<<(NN + 63) / 64, 256, 0, stream>>>(X, params + 1152, params + 1152 + 5120, flags, d_out, NN);
}